// Round 1
// baseline (461.573 us; speedup 1.0000x reference)
//
#include <hip/hip_runtime.h>

typedef _Float16 h16;
typedef h16 half8 __attribute__((ext_vector_type(8)));
typedef h16 half4v __attribute__((ext_vector_type(4)));
typedef float f32x4 __attribute__((ext_vector_type(4)));

#define BB 4
#define SS 2048
#define EE 1024
#define HH 16
#define DH 64

__device__ __forceinline__ void gload_lds16(const void* g, void* l) {
  __builtin_amdgcn_global_load_lds((const __attribute__((address_space(1))) void*)g,
                                   (__attribute__((address_space(3))) void*)l, 16, 0, 0);
}

// ---------------- mask pack: int32 -> bitmask ----------------
__global__ __launch_bounds__(256) void mha_pack_mask(const int* __restrict__ mask,
                                                     unsigned* __restrict__ maskw) {
  int gid = blockIdx.x * 256 + threadIdx.x;
  unsigned long long bal = __ballot(mask[gid] != 0);
  int lane = threadIdx.x & 63;
  if (lane == 0) maskw[gid >> 5] = (unsigned)bal;
  else if (lane == 32) maskw[gid >> 5] = (unsigned)(bal >> 32);
}

// ---------------- weight transpose + fp32->fp16 ----------------
__global__ __launch_bounds__(256) void mha_wtrans(const float* __restrict__ w0, const float* __restrict__ w1,
                                                  const float* __restrict__ w2, const float* __restrict__ w3,
                                                  h16* __restrict__ o0, h16* __restrict__ o1,
                                                  h16* __restrict__ o2, h16* __restrict__ o3) {
  __shared__ float t[32][33];
  int z = blockIdx.z;
  const float* src = z == 0 ? w0 : z == 1 ? w1 : z == 2 ? w2 : w3;
  h16* dst = z == 0 ? o0 : z == 1 ? o1 : z == 2 ? o2 : o3;
  int x = threadIdx.x, y = threadIdx.y;
  int bx = blockIdx.x * 32, by = blockIdx.y * 32;
#pragma unroll
  for (int i = 0; i < 4; ++i)
    t[y + i * 8][x] = src[(size_t)(by + y + i * 8) * EE + bx + x];
  __syncthreads();
#pragma unroll
  for (int i = 0; i < 4; ++i)
    dst[(size_t)(bx + y + i * 8) * EE + by + x] = (h16)t[x][y + i * 8];
}

// ---------------- QKV projection GEMM (128x128 tile, BK=32) ----------------
#define PTM 128
#define PTN 128
#define PBK 32

__global__ __launch_bounds__(256) void mha_proj(
    const float* __restrict__ Xq, const float* __restrict__ Xk, const float* __restrict__ Xv,
    const h16* __restrict__ Wqt, const h16* __restrict__ Wkt, const h16* __restrict__ Wvt,
    const float* __restrict__ bq, const float* __restrict__ bk, const float* __restrict__ bv,
    h16* __restrict__ Oq, h16* __restrict__ Ok, h16* __restrict__ Ov) {
  int z = blockIdx.z;
  const float* X = z == 0 ? Xq : z == 1 ? Xk : Xv;
  const h16* Wt = z == 0 ? Wqt : z == 1 ? Wkt : Wvt;
  const float* bias = z == 0 ? bq : z == 1 ? bk : bv;
  h16* out = z == 0 ? Oq : z == 1 ? Ok : Ov;

  __shared__ __align__(16) h16 As[PTM * PBK];
  __shared__ __align__(16) h16 Bs[PTN * PBK];

  int tid = threadIdx.x;
  int lane = tid & 63, wid = tid >> 6;
  int l15 = lane & 15, l4 = lane >> 4;
  int wr = wid >> 1, wc = wid & 1;
  int mbase = blockIdx.y * PTM;
  int nbase = blockIdx.x * PTN;

  const f32x4 fz = {0.f, 0.f, 0.f, 0.f};
  f32x4 acc[4][4];
#pragma unroll
  for (int i = 0; i < 4; ++i)
#pragma unroll
    for (int j = 0; j < 4; ++j) acc[i][j] = fz;

  int brow0 = wid * 32 + (lane >> 2);
  int bchunk = lane & 3;

  for (int kt = 0; kt < EE; kt += PBK) {
    // A: fp32 -> fp16 reg staging
#pragma unroll
    for (int i = 0; i < 4; ++i) {
      int flat = i * 1024 + tid * 4;
      int row = flat >> 5;
      int col = flat & 31;
      const float4 xv = *reinterpret_cast<const float4*>(&X[(size_t)(mbase + row) * EE + kt + col]);
      half4v hv = {(h16)xv.x, (h16)xv.y, (h16)xv.z, (h16)xv.w};
      *reinterpret_cast<half4v*>(&As[row * PBK + col]) = hv;
    }
    // B: async global->LDS
#pragma unroll
    for (int c = 0; c < 2; ++c) {
      int row = brow0 + c * 16;
      gload_lds16(&Wt[(size_t)(nbase + row) * EE + kt + bchunk * 8], &Bs[wid * 1024 + c * 512]);
    }
    __syncthreads();

    half8 a[4], bfr[4];
#pragma unroll
    for (int i = 0; i < 4; ++i) {
      a[i] = *reinterpret_cast<const half8*>(&As[(wr * 64 + i * 16 + l15) * PBK + l4 * 8]);
      bfr[i] = *reinterpret_cast<const half8*>(&Bs[(wc * 64 + i * 16 + l15) * PBK + l4 * 8]);
    }
#pragma unroll
    for (int mi = 0; mi < 4; ++mi)
#pragma unroll
      for (int ni = 0; ni < 4; ++ni)
        acc[mi][ni] = __builtin_amdgcn_mfma_f32_16x16x32_f16(a[mi], bfr[ni], acc[mi][ni], 0, 0, 0);
    __syncthreads();
  }

#pragma unroll
  for (int mi = 0; mi < 4; ++mi) {
#pragma unroll
    for (int ni = 0; ni < 4; ++ni) {
      int n = nbase + wc * 64 + ni * 16 + l15;
      float bv_ = bias[n];
      int h = n >> 6, d = n & 63;
#pragma unroll
      for (int j = 0; j < 4; ++j) {
        int m = mbase + wr * 64 + mi * 16 + l4 * 4 + j;
        int b_ = m >> 11, s = m & 2047;
        h16 hv = (h16)(acc[mi][ni][j] + bv_);
        if (z != 2)
          out[(((size_t)(b_ * HH + h)) * SS + s) * DH + d] = hv;       // (B,H,S,D)
        else
          out[(((size_t)(b_ * HH + h)) * DH + d) * SS + s] = hv;       // V transposed (B,H,D,S)
      }
    }
  }
}

// ---------------- flash attention ----------------
__global__ __launch_bounds__(256) void mha_attn(
    const h16* __restrict__ qh, const h16* __restrict__ kh, const h16* __restrict__ vh,
    const unsigned* __restrict__ maskw, h16* __restrict__ ah) {
  __shared__ __align__(16) h16 Ks[64 * 64];
  __shared__ __align__(16) h16 Vs[64 * 64];
  __shared__ __align__(16) h16 Ps[4 * 32 * 64];

  int bh = blockIdx.y;
  int b_ = bh >> 4, hh = bh & 15;
  int tid = threadIdx.x, lane = tid & 63, wid = tid >> 6;
  int l15 = lane & 15, l4 = lane >> 4;

  const h16* Qb = qh + (size_t)bh * SS * DH;
  const h16* Kb = kh + (size_t)bh * SS * DH;
  const h16* Vb = vh + (size_t)bh * DH * SS;
  int qrow0 = blockIdx.x * 128 + wid * 32;

  half8 qf[2][2];
#pragma unroll
  for (int mi = 0; mi < 2; ++mi)
#pragma unroll
    for (int kk = 0; kk < 2; ++kk)
      qf[mi][kk] = *reinterpret_cast<const half8*>(&Qb[(size_t)(qrow0 + mi * 16 + l15) * DH + kk * 32 + l4 * 8]);

  float m_run[2][4], l_run[2][4];
  f32x4 oacc[2][4];
  const f32x4 fz = {0.f, 0.f, 0.f, 0.f};
#pragma unroll
  for (int mi = 0; mi < 2; ++mi) {
#pragma unroll
    for (int j = 0; j < 4; ++j) { m_run[mi][j] = -1e30f; l_run[mi][j] = 0.f; }
#pragma unroll
    for (int di = 0; di < 4; ++di) oacc[mi][di] = fz;
  }

  const unsigned* mwb = maskw + ((size_t)b_ * SS + qrow0) * 64;

  int srow = wid * 16 + (lane >> 3);
  int schunk = lane & 7;

  for (int tt = 0; tt < SS; tt += 64) {
    // stage K,V tiles (XOR-swizzled: LDS linear, source chunk permuted)
#pragma unroll
    for (int c = 0; c < 2; ++c) {
      int r = srow + c * 8;
      int gk = schunk ^ (r & 7);
      gload_lds16(&Kb[(size_t)(tt + r) * DH + gk * 8], &Ks[wid * 1024 + c * 512]);
      gload_lds16(&Vb[(size_t)r * SS + tt + gk * 8], &Vs[wid * 1024 + c * 512]);
    }
    __syncthreads();

    // QK^T
    half8 kf[4][2];
#pragma unroll
    for (int ni = 0; ni < 4; ++ni) {
      int trow = ni * 16 + l15;
      int sw = trow & 7;
      kf[ni][0] = *reinterpret_cast<const half8*>(&Ks[trow * 64 + (l4 ^ sw) * 8]);
      kf[ni][1] = *reinterpret_cast<const half8*>(&Ks[trow * 64 + ((4 + l4) ^ sw) * 8]);
    }
    f32x4 sf[2][4];
#pragma unroll
    for (int mi = 0; mi < 2; ++mi)
#pragma unroll
      for (int ni = 0; ni < 4; ++ni) {
        f32x4 t_ = fz;
        t_ = __builtin_amdgcn_mfma_f32_16x16x32_f16(qf[mi][0], kf[ni][0], t_, 0, 0, 0);
        t_ = __builtin_amdgcn_mfma_f32_16x16x32_f16(qf[mi][1], kf[ni][1], t_, 0, 0, 0);
        sf[mi][ni] = t_;
      }

    // mask (true -> blocked)
    int tw = tt >> 5;
#pragma unroll
    for (int mi = 0; mi < 2; ++mi)
#pragma unroll
      for (int j = 0; j < 4; ++j) {
        int rl = mi * 16 + l4 * 4 + j;
        unsigned w0 = mwb[rl * 64 + tw];
        unsigned w1 = mwb[rl * 64 + tw + 1];
#pragma unroll
        for (int ni = 0; ni < 4; ++ni) {
          int col = ni * 16 + l15;
          unsigned w = (ni < 2) ? w0 : w1;
          if ((w >> (col & 31)) & 1) sf[mi][ni][j] = -1e30f;
        }
      }

    // online softmax (wave-parallel, per-row reduce across 16-lane column group)
    float sc_[2][4];
#pragma unroll
    for (int mi = 0; mi < 2; ++mi)
#pragma unroll
      for (int j = 0; j < 4; ++j) {
        float tmax = fmaxf(fmaxf(sf[mi][0][j], sf[mi][1][j]), fmaxf(sf[mi][2][j], sf[mi][3][j]));
        tmax = fmaxf(tmax, __shfl_xor(tmax, 1));
        tmax = fmaxf(tmax, __shfl_xor(tmax, 2));
        tmax = fmaxf(tmax, __shfl_xor(tmax, 4));
        tmax = fmaxf(tmax, __shfl_xor(tmax, 8));
        float mold = m_run[mi][j];
        float mnew = fmaxf(mold, tmax);
        float sc = __expf(mold - mnew);
        float psum = 0.f;
#pragma unroll
        for (int ni = 0; ni < 4; ++ni) {
          float sv = sf[mi][ni][j];
          float p = __expf(sv - mnew);
          p = (sv < -1e29f) ? 0.f : p;
          sf[mi][ni][j] = p;
          psum += p;
        }
        psum += __shfl_xor(psum, 1);
        psum += __shfl_xor(psum, 2);
        psum += __shfl_xor(psum, 4);
        psum += __shfl_xor(psum, 8);
        l_run[mi][j] = l_run[mi][j] * sc + psum;
        m_run[mi][j] = mnew;
        sc_[mi][j] = sc;
      }
#pragma unroll
    for (int mi = 0; mi < 2; ++mi)
#pragma unroll
      for (int di = 0; di < 4; ++di) {
        f32x4 o = oacc[mi][di];
        o[0] *= sc_[mi][0]; o[1] *= sc_[mi][1]; o[2] *= sc_[mi][2]; o[3] *= sc_[mi][3];
        oacc[mi][di] = o;
      }

    // P -> LDS (per-wave buffer, swizzled) for A-fragment relayout
    h16* Pw = &Ps[wid * 2048];
#pragma unroll
    for (int mi = 0; mi < 2; ++mi)
#pragma unroll
      for (int ni = 0; ni < 4; ++ni)
#pragma unroll
        for (int j = 0; j < 4; ++j) {
          int rl = mi * 16 + l4 * 4 + j;
          int col = ni * 16 + l15;
          int ch = (col >> 3) ^ (rl & 7);
          Pw[rl * 64 + ch * 8 + (col & 7)] = (h16)sf[mi][ni][j];
        }

    // PV
    half8 vf[4][2], pf[2][2];
#pragma unroll
    for (int di = 0; di < 4; ++di) {
      int dr = di * 16 + l15, sw = dr & 7;
      vf[di][0] = *reinterpret_cast<const half8*>(&Vs[dr * 64 + (l4 ^ sw) * 8]);
      vf[di][1] = *reinterpret_cast<const half8*>(&Vs[dr * 64 + ((4 + l4) ^ sw) * 8]);
    }
#pragma unroll
    for (int mi = 0; mi < 2; ++mi) {
      int pr = mi * 16 + l15, sw = pr & 7;
      pf[mi][0] = *reinterpret_cast<const half8*>(&Pw[pr * 64 + (l4 ^ sw) * 8]);
      pf[mi][1] = *reinterpret_cast<const half8*>(&Pw[pr * 64 + ((4 + l4) ^ sw) * 8]);
    }
#pragma unroll
    for (int mi = 0; mi < 2; ++mi)
#pragma unroll
      for (int di = 0; di < 4; ++di) {
        oacc[mi][di] = __builtin_amdgcn_mfma_f32_16x16x32_f16(pf[mi][0], vf[di][0], oacc[mi][di], 0, 0, 0);
        oacc[mi][di] = __builtin_amdgcn_mfma_f32_16x16x32_f16(pf[mi][1], vf[di][1], oacc[mi][di], 0, 0, 0);
      }

    __syncthreads();
  }

  // epilogue: /= (l * sqrt(64)), store (B,S,H,D) fp16
  h16* Ob = ah + ((size_t)b_ * SS + qrow0) * EE + hh * DH;
#pragma unroll
  for (int mi = 0; mi < 2; ++mi) {
    float inv[4];
#pragma unroll
    for (int j = 0; j < 4; ++j) inv[j] = 1.f / (l_run[mi][j] * 8.f);
#pragma unroll
    for (int di = 0; di < 4; ++di)
#pragma unroll
      for (int j = 0; j < 4; ++j) {
        int rl = mi * 16 + l4 * 4 + j;
        Ob[(size_t)rl * EE + di * 16 + l15] = (h16)(oacc[mi][di][j] * inv[j]);
      }
  }
}

// ---------------- output projection GEMM ----------------
__global__ __launch_bounds__(256) void mha_oproj(
    const h16* __restrict__ A, const h16* __restrict__ Wot,
    const float* __restrict__ bo, float* __restrict__ out) {
  __shared__ __align__(16) h16 As[PTM * PBK];
  __shared__ __align__(16) h16 Bs[PTN * PBK];
  int tid = threadIdx.x, lane = tid & 63, wid = tid >> 6;
  int l15 = lane & 15, l4 = lane >> 4;
  int wr = wid >> 1, wc = wid & 1;
  int mbase = blockIdx.y * PTM, nbase = blockIdx.x * PTN;
  const f32x4 fz = {0.f, 0.f, 0.f, 0.f};
  f32x4 acc[4][4];
#pragma unroll
  for (int i = 0; i < 4; ++i)
#pragma unroll
    for (int j = 0; j < 4; ++j) acc[i][j] = fz;
  int row0 = wid * 32 + (lane >> 2), chunk = lane & 3;
  for (int kt = 0; kt < EE; kt += PBK) {
#pragma unroll
    for (int c = 0; c < 2; ++c) {
      int r = row0 + c * 16;
      gload_lds16(&A[(size_t)(mbase + r) * EE + kt + chunk * 8], &As[wid * 1024 + c * 512]);
      gload_lds16(&Wot[(size_t)(nbase + r) * EE + kt + chunk * 8], &Bs[wid * 1024 + c * 512]);
    }
    __syncthreads();
    half8 a[4], bfr[4];
#pragma unroll
    for (int i = 0; i < 4; ++i) {
      a[i] = *reinterpret_cast<const half8*>(&As[(wr * 64 + i * 16 + l15) * PBK + l4 * 8]);
      bfr[i] = *reinterpret_cast<const half8*>(&Bs[(wc * 64 + i * 16 + l15) * PBK + l4 * 8]);
    }
#pragma unroll
    for (int mi = 0; mi < 4; ++mi)
#pragma unroll
      for (int ni = 0; ni < 4; ++ni)
        acc[mi][ni] = __builtin_amdgcn_mfma_f32_16x16x32_f16(a[mi], bfr[ni], acc[mi][ni], 0, 0, 0);
    __syncthreads();
  }
#pragma unroll
  for (int mi = 0; mi < 4; ++mi)
#pragma unroll
    for (int ni = 0; ni < 4; ++ni) {
      int n = nbase + wc * 64 + ni * 16 + l15;
      float bb = bo[n];
#pragma unroll
      for (int j = 0; j < 4; ++j) {
        int m = mbase + wr * 64 + mi * 16 + l4 * 4 + j;
        out[(size_t)m * EE + n] = acc[mi][ni][j] + bb;
      }
    }
}

extern "C" void kernel_launch(void* const* d_in, const int* in_sizes, int n_in,
                              void* d_out, int out_size, void* d_ws, size_t ws_size,
                              hipStream_t stream) {
  const float* query = (const float*)d_in[0];
  const float* key_ = (const float*)d_in[1];
  const float* value = (const float*)d_in[2];
  const int* mask = (const int*)d_in[3];
  const float* Wq = (const float*)d_in[4];
  const float* bq = (const float*)d_in[5];
  const float* Wk = (const float*)d_in[6];
  const float* bk = (const float*)d_in[7];
  const float* Wv = (const float*)d_in[8];
  const float* bv = (const float*)d_in[9];
  const float* Wo = (const float*)d_in[10];
  const float* bo = (const float*)d_in[11];
  float* out = (float*)d_out;

  const size_t MH = 1u << 20;                 // halves per 1024x1024 weight
  const size_t QH = (size_t)BB * HH * SS * DH; // 8388608 halves
  h16* wqt = (h16*)d_ws;
  h16* wkt = wqt + MH;
  h16* wvt = wkt + MH;
  h16* wot = wvt + MH;
  h16* qh = wot + MH;
  h16* kh = qh + QH;
  h16* vh = kh + QH;
  h16* ah = vh + QH;
  unsigned* maskw = (unsigned*)(ah + QH);

  mha_pack_mask<<<(BB * SS * SS) / 256, 256, 0, stream>>>(mask, maskw);
  mha_wtrans<<<dim3(32, 32, 4), dim3(32, 8), 0, stream>>>(Wq, Wk, Wv, Wo, wqt, wkt, wvt, wot);
  mha_proj<<<dim3(EE / PTN, (BB * SS) / PTM, 3), 256, 0, stream>>>(
      query, key_, value, wqt, wkt, wvt, bq, bk, bv, qh, kh, vh);
  mha_attn<<<dim3(SS / 128, BB * HH), 256, 0, stream>>>(qh, kh, vh, maskw, ah);
  mha_oproj<<<dim3(EE / PTN, (BB * SS) / PTM), 256, 0, stream>>>(ah, wot, bo, out);
}

// Round 2
// 403.262 us; speedup vs baseline: 1.1446x; 1.1446x over previous
//
#include <hip/hip_runtime.h>

typedef _Float16 h16;
typedef h16 half8 __attribute__((ext_vector_type(8)));
typedef h16 half4v __attribute__((ext_vector_type(4)));
typedef float f32x4 __attribute__((ext_vector_type(4)));

#define BB 4
#define SS 2048
#define EE 1024
#define HH 16
#define DH 64

__device__ __forceinline__ void gload_lds16(const void* g, void* l) {
  __builtin_amdgcn_global_load_lds((const __attribute__((address_space(1))) void*)g,
                                   (__attribute__((address_space(3))) void*)l, 16, 0, 0);
}

// ---------------- mask pack: int32 -> bitmask ----------------
__global__ __launch_bounds__(256) void mha_pack_mask(const int* __restrict__ mask,
                                                     unsigned* __restrict__ maskw) {
  int gid = blockIdx.x * 256 + threadIdx.x;
  unsigned long long bal = __ballot(mask[gid] != 0);
  int lane = threadIdx.x & 63;
  if (lane == 0) maskw[gid >> 5] = (unsigned)bal;
  else if (lane == 32) maskw[gid >> 5] = (unsigned)(bal >> 32);
}

// ---------------- weight transpose + fp32->fp16 ----------------
__global__ __launch_bounds__(256) void mha_wtrans(const float* __restrict__ w0, const float* __restrict__ w1,
                                                  const float* __restrict__ w2, const float* __restrict__ w3,
                                                  h16* __restrict__ o0, h16* __restrict__ o1,
                                                  h16* __restrict__ o2, h16* __restrict__ o3) {
  __shared__ float t[32][33];
  int z = blockIdx.z;
  const float* src = z == 0 ? w0 : z == 1 ? w1 : z == 2 ? w2 : w3;
  h16* dst = z == 0 ? o0 : z == 1 ? o1 : z == 2 ? o2 : o3;
  int x = threadIdx.x, y = threadIdx.y;
  int bx = blockIdx.x * 32, by = blockIdx.y * 32;
#pragma unroll
  for (int i = 0; i < 4; ++i)
    t[y + i * 8][x] = src[(size_t)(by + y + i * 8) * EE + bx + x];
  __syncthreads();
#pragma unroll
  for (int i = 0; i < 4; ++i)
    dst[(size_t)(bx + y + i * 8) * EE + by + x] = (h16)t[x][y + i * 8];
}

// ---------------- QKV projection GEMM (128x128 tile, BK=32) ----------------
#define PTM 128
#define PTN 128
#define PBK 32

__global__ __launch_bounds__(256) void mha_proj(
    const float* __restrict__ Xq, const float* __restrict__ Xk, const float* __restrict__ Xv,
    const h16* __restrict__ Wqt, const h16* __restrict__ Wkt, const h16* __restrict__ Wvt,
    const float* __restrict__ bq, const float* __restrict__ bk, const float* __restrict__ bv,
    h16* __restrict__ Oq, h16* __restrict__ Ok, h16* __restrict__ Ov) {
  int z = blockIdx.z;
  const float* X = z == 0 ? Xq : z == 1 ? Xk : Xv;
  const h16* Wt = z == 0 ? Wqt : z == 1 ? Wkt : Wvt;
  const float* bias = z == 0 ? bq : z == 1 ? bk : bv;
  h16* out = z == 0 ? Oq : z == 1 ? Ok : Ov;

  __shared__ __align__(16) h16 As[PTM * PBK];
  __shared__ __align__(16) h16 Bs[PTN * PBK];

  int tid = threadIdx.x;
  int lane = tid & 63, wid = tid >> 6;
  int l15 = lane & 15, l4 = lane >> 4;
  int wr = wid >> 1, wc = wid & 1;
  int mbase = blockIdx.y * PTM;
  int nbase = blockIdx.x * PTN;

  const f32x4 fz = {0.f, 0.f, 0.f, 0.f};
  f32x4 acc[4][4];
#pragma unroll
  for (int i = 0; i < 4; ++i)
#pragma unroll
    for (int j = 0; j < 4; ++j) acc[i][j] = fz;

  int brow0 = wid * 32 + (lane >> 2);
  int bchunk = lane & 3;

  for (int kt = 0; kt < EE; kt += PBK) {
    // A: fp32 -> fp16 reg staging
#pragma unroll
    for (int i = 0; i < 4; ++i) {
      int flat = i * 1024 + tid * 4;
      int row = flat >> 5;
      int col = flat & 31;
      const float4 xv = *reinterpret_cast<const float4*>(&X[(size_t)(mbase + row) * EE + kt + col]);
      half4v hv = {(h16)xv.x, (h16)xv.y, (h16)xv.z, (h16)xv.w};
      *reinterpret_cast<half4v*>(&As[row * PBK + col]) = hv;
    }
    // B: async global->LDS
#pragma unroll
    for (int c = 0; c < 2; ++c) {
      int row = brow0 + c * 16;
      gload_lds16(&Wt[(size_t)(nbase + row) * EE + kt + bchunk * 8], &Bs[wid * 1024 + c * 512]);
    }
    __syncthreads();

    half8 a[4], bfr[4];
#pragma unroll
    for (int i = 0; i < 4; ++i) {
      a[i] = *reinterpret_cast<const half8*>(&As[(wr * 64 + i * 16 + l15) * PBK + l4 * 8]);
      bfr[i] = *reinterpret_cast<const half8*>(&Bs[(wc * 64 + i * 16 + l15) * PBK + l4 * 8]);
    }
#pragma unroll
    for (int mi = 0; mi < 4; ++mi)
#pragma unroll
      for (int ni = 0; ni < 4; ++ni)
        acc[mi][ni] = __builtin_amdgcn_mfma_f32_16x16x32_f16(a[mi], bfr[ni], acc[mi][ni], 0, 0, 0);
    __syncthreads();
  }

  // Q is pre-scaled by log2(e) so attention can use exp2 directly.
  const float qscale = (z == 0) ? 1.44269504088896f : 1.0f;
#pragma unroll
  for (int mi = 0; mi < 4; ++mi) {
#pragma unroll
    for (int ni = 0; ni < 4; ++ni) {
      int n = nbase + wc * 64 + ni * 16 + l15;
      float bv_ = bias[n];
      int h = n >> 6, d = n & 63;
#pragma unroll
      for (int j = 0; j < 4; ++j) {
        int m = mbase + wr * 64 + mi * 16 + l4 * 4 + j;
        int b_ = m >> 11, s = m & 2047;
        h16 hv = (h16)((acc[mi][ni][j] + bv_) * qscale);
        if (z != 2)
          out[(((size_t)(b_ * HH + h)) * SS + s) * DH + d] = hv;       // (B,H,S,D)
        else
          out[(((size_t)(b_ * HH + h)) * DH + d) * SS + s] = hv;       // V transposed (B,H,D,S)
      }
    }
  }
}

// ---------------- flash attention (swapped QK^T, log2-domain softmax) ----------------
__global__ __launch_bounds__(256) void mha_attn(
    const h16* __restrict__ qh, const h16* __restrict__ kh, const h16* __restrict__ vh,
    const unsigned* __restrict__ maskw, h16* __restrict__ ah) {
  __shared__ __align__(16) h16 Ks[2][64 * 64];
  __shared__ __align__(16) h16 Vs[2][64 * 64];
  __shared__ __align__(16) h16 Ps[4][32 * 64];

  int bh = blockIdx.y;
  int b_ = bh >> 4, hh = bh & 15;
  int tid = threadIdx.x, lane = tid & 63, wid = tid >> 6;
  int l15 = lane & 15, l4 = lane >> 4;

  const h16* Qb = qh + (size_t)bh * SS * DH;
  const h16* Kb = kh + (size_t)bh * SS * DH;
  const h16* Vb = vh + (size_t)bh * DH * SS;
  int qrow0 = blockIdx.x * 128 + wid * 32;

  // Q fragments (B-operand layout): lane holds Q[q = l15][k = l4*8..]
  half8 qf[2][2];
#pragma unroll
  for (int mi = 0; mi < 2; ++mi)
#pragma unroll
    for (int kk = 0; kk < 2; ++kk)
      qf[mi][kk] = *reinterpret_cast<const half8*>(&Qb[(size_t)(qrow0 + mi * 16 + l15) * DH + kk * 32 + l4 * 8]);

  float m_run[2] = {-1e30f, -1e30f};
  float l_run[2] = {0.f, 0.f};
  f32x4 oacc[2][4];
  const f32x4 fz = {0.f, 0.f, 0.f, 0.f};
#pragma unroll
  for (int mi = 0; mi < 2; ++mi)
#pragma unroll
    for (int di = 0; di < 4; ++di) oacc[mi][di] = fz;

  const unsigned* mwb = maskw + ((size_t)b_ * SS + qrow0) * 64;

  int srow = wid * 16 + (lane >> 3);
  int schunk = lane & 7;

  // prologue: stage tile 0 into buffer 0 + its mask words
#pragma unroll
  for (int c = 0; c < 2; ++c) {
    int r = srow + c * 8;
    int gk = schunk ^ (r & 7);
    gload_lds16(&Kb[(size_t)r * DH + gk * 8], &Ks[0][wid * 1024 + c * 512]);
    gload_lds16(&Vb[(size_t)r * SS + gk * 8], &Vs[0][wid * 1024 + c * 512]);
  }
  unsigned mw[2][2];
  mw[0][0] = mwb[l15 * 64 + 0];
  mw[0][1] = mwb[l15 * 64 + 1];
  mw[1][0] = mwb[(16 + l15) * 64 + 0];
  mw[1][1] = mwb[(16 + l15) * 64 + 1];
  __syncthreads();

  h16* Pw = &Ps[wid][0];
  int it = 0;
  for (int tt = 0; tt < SS; tt += 64, it ^= 1) {
    // prefetch next tile (double buffer) + next mask words; drained at the
    // __syncthreads() below, i.e. hidden under this tile's compute.
    unsigned mwn[2][2] = {{0u, 0u}, {0u, 0u}};
    if (tt + 64 < SS) {
#pragma unroll
      for (int c = 0; c < 2; ++c) {
        int r = srow + c * 8;
        int gk = schunk ^ (r & 7);
        gload_lds16(&Kb[(size_t)(tt + 64 + r) * DH + gk * 8], &Ks[it ^ 1][wid * 1024 + c * 512]);
        gload_lds16(&Vb[(size_t)r * SS + tt + 64 + gk * 8], &Vs[it ^ 1][wid * 1024 + c * 512]);
      }
      int tw = (tt + 64) >> 5;
      mwn[0][0] = mwb[l15 * 64 + tw];
      mwn[0][1] = mwb[l15 * 64 + tw + 1];
      mwn[1][0] = mwb[(16 + l15) * 64 + tw];
      mwn[1][1] = mwb[(16 + l15) * 64 + tw + 1];
    }

    // QK^T, swapped operands: st[mi][ni] = S^T fragment, row = t, col = q
    const h16* Kt = &Ks[it][0];
    half8 kf[4][2];
#pragma unroll
    for (int ni = 0; ni < 4; ++ni) {
      int trow = ni * 16 + l15;
      int sw = trow & 7;
      kf[ni][0] = *reinterpret_cast<const half8*>(&Kt[trow * 64 + (l4 ^ sw) * 8]);
      kf[ni][1] = *reinterpret_cast<const half8*>(&Kt[trow * 64 + ((4 + l4) ^ sw) * 8]);
    }
    f32x4 st[2][4];
    __builtin_amdgcn_s_setprio(1);
#pragma unroll
    for (int mi = 0; mi < 2; ++mi)
#pragma unroll
      for (int ni = 0; ni < 4; ++ni) {
        f32x4 t_ = fz;
        t_ = __builtin_amdgcn_mfma_f32_16x16x32_f16(kf[ni][0], qf[mi][0], t_, 0, 0, 0);
        t_ = __builtin_amdgcn_mfma_f32_16x16x32_f16(kf[ni][1], qf[mi][1], t_, 0, 0, 0);
        st[mi][ni] = t_;
      }
    __builtin_amdgcn_s_setprio(0);

    // mask: lane owns q = mi*16+l15, t = ni*16 + l4*4 + j
#pragma unroll
    for (int mi = 0; mi < 2; ++mi) {
      unsigned b0 = mw[mi][0] >> (l4 * 4);
      unsigned b1 = mw[mi][0] >> (l4 * 4 + 16);
      unsigned b2 = mw[mi][1] >> (l4 * 4);
      unsigned b3 = mw[mi][1] >> (l4 * 4 + 16);
#pragma unroll
      for (int j = 0; j < 4; ++j) {
        if ((b0 >> j) & 1) st[mi][0][j] = -1e30f;
        if ((b1 >> j) & 1) st[mi][1][j] = -1e30f;
        if ((b2 >> j) & 1) st[mi][2][j] = -1e30f;
        if ((b3 >> j) & 1) st[mi][3][j] = -1e30f;
      }
    }

    // online softmax, log2 domain; per-lane row-local reduce + 2 shfl
#pragma unroll
    for (int mi = 0; mi < 2; ++mi) {
      f32x4 mx4;
#pragma unroll
      for (int j = 0; j < 4; ++j)
        mx4[j] = fmaxf(fmaxf(st[mi][0][j], st[mi][1][j]), fmaxf(st[mi][2][j], st[mi][3][j]));
      float tmax = fmaxf(fmaxf(mx4[0], mx4[1]), fmaxf(mx4[2], mx4[3]));
      tmax = fmaxf(tmax, __shfl_xor(tmax, 16));
      tmax = fmaxf(tmax, __shfl_xor(tmax, 32));
      // T13 defer-max: only rescale when the max grew by > 8 (2^8 headroom)
      if (!__all(tmax - m_run[mi] <= 8.0f)) {
        float mnew = fmaxf(m_run[mi], tmax);
        float sc = exp2f(m_run[mi] - mnew);
        l_run[mi] *= sc;
#pragma unroll
        for (int di = 0; di < 4; ++di) oacc[mi][di] *= sc;
        m_run[mi] = mnew;
      }
      float mneg = -m_run[mi];
#pragma unroll
      for (int ni = 0; ni < 4; ++ni)
#pragma unroll
        for (int j = 0; j < 4; ++j)
          st[mi][ni][j] = exp2f(st[mi][ni][j] + mneg);
      f32x4 ps4 = (st[mi][0] + st[mi][1]) + (st[mi][2] + st[mi][3]);
      float psum = (ps4[0] + ps4[1]) + (ps4[2] + ps4[3]);
      psum += __shfl_xor(psum, 16);
      psum += __shfl_xor(psum, 32);
      l_run[mi] += psum;
    }

    // pack P -> per-wave LDS [q][t], 16B-chunk XOR swizzle
#pragma unroll
    for (int mi = 0; mi < 2; ++mi) {
      int q = mi * 16 + l15;
#pragma unroll
      for (int ni = 0; ni < 4; ++ni) {
        auto pa = __builtin_amdgcn_cvt_pkrtz(st[mi][ni][0], st[mi][ni][1]);
        auto pb = __builtin_amdgcn_cvt_pkrtz(st[mi][ni][2], st[mi][ni][3]);
        half4v w;
        w[0] = pa[0]; w[1] = pa[1]; w[2] = pb[0]; w[3] = pb[1];
        int c16 = (ni * 2 + (l4 >> 1)) ^ (q & 7);
        *reinterpret_cast<half4v*>(&Pw[q * 64 + c16 * 8 + (l4 & 1) * 4]) = w;
      }
    }

    // PV: O^T += V^T * P^T  (row = d, col = q)
    const h16* Vt = &Vs[it][0];
    half8 vf[4][2], pf[2][2];
#pragma unroll
    for (int di = 0; di < 4; ++di) {
      int dr = di * 16 + l15, sw = dr & 7;
      vf[di][0] = *reinterpret_cast<const half8*>(&Vt[dr * 64 + (l4 ^ sw) * 8]);
      vf[di][1] = *reinterpret_cast<const half8*>(&Vt[dr * 64 + ((4 + l4) ^ sw) * 8]);
    }
#pragma unroll
    for (int mi = 0; mi < 2; ++mi) {
      int q = mi * 16 + l15;
      int c0 = (l4 ^ (q & 7)) * 8;
      int c1 = ((4 + l4) ^ (q & 7)) * 8;
      half4v p00 = *reinterpret_cast<const half4v*>(&Pw[q * 64 + c0]);
      half4v p01 = *reinterpret_cast<const half4v*>(&Pw[q * 64 + c0 + 4]);
      half4v p10 = *reinterpret_cast<const half4v*>(&Pw[q * 64 + c1]);
      half4v p11 = *reinterpret_cast<const half4v*>(&Pw[q * 64 + c1 + 4]);
#pragma unroll
      for (int e = 0; e < 4; ++e) {
        pf[mi][0][e] = p00[e]; pf[mi][0][e + 4] = p01[e];
        pf[mi][1][e] = p10[e]; pf[mi][1][e + 4] = p11[e];
      }
    }
    __builtin_amdgcn_s_setprio(1);
#pragma unroll
    for (int mi = 0; mi < 2; ++mi)
#pragma unroll
      for (int di = 0; di < 4; ++di) {
        oacc[mi][di] = __builtin_amdgcn_mfma_f32_16x16x32_f16(vf[di][0], pf[mi][0], oacc[mi][di], 0, 0, 0);
        oacc[mi][di] = __builtin_amdgcn_mfma_f32_16x16x32_f16(vf[di][1], pf[mi][1], oacc[mi][di], 0, 0, 0);
      }
    __builtin_amdgcn_s_setprio(0);

    mw[0][0] = mwn[0][0]; mw[0][1] = mwn[0][1];
    mw[1][0] = mwn[1][0]; mw[1][1] = mwn[1][1];
    __syncthreads();
  }

  // epilogue: /= (l * sqrt(64)); lane owns q = mi*16+l15, d = di*16+l4*4+j
#pragma unroll
  for (int mi = 0; mi < 2; ++mi) {
    float inv = 1.f / (l_run[mi] * 8.f);
    size_t rowb = ((size_t)b_ * SS + (qrow0 + mi * 16 + l15)) * EE + hh * DH;
#pragma unroll
    for (int di = 0; di < 4; ++di) {
      half4v w;
#pragma unroll
      for (int j = 0; j < 4; ++j) w[j] = (h16)(oacc[mi][di][j] * inv);
      *reinterpret_cast<half4v*>(&ah[rowb + di * 16 + l4 * 4]) = w;
    }
  }
}

// ---------------- output projection GEMM ----------------
__global__ __launch_bounds__(256) void mha_oproj(
    const h16* __restrict__ A, const h16* __restrict__ Wot,
    const float* __restrict__ bo, float* __restrict__ out) {
  __shared__ __align__(16) h16 As[PTM * PBK];
  __shared__ __align__(16) h16 Bs[PTN * PBK];
  int tid = threadIdx.x, lane = tid & 63, wid = tid >> 6;
  int l15 = lane & 15, l4 = lane >> 4;
  int wr = wid >> 1, wc = wid & 1;
  int mbase = blockIdx.y * PTM, nbase = blockIdx.x * PTN;
  const f32x4 fz = {0.f, 0.f, 0.f, 0.f};
  f32x4 acc[4][4];
#pragma unroll
  for (int i = 0; i < 4; ++i)
#pragma unroll
    for (int j = 0; j < 4; ++j) acc[i][j] = fz;
  int row0 = wid * 32 + (lane >> 2), chunk = lane & 3;
  for (int kt = 0; kt < EE; kt += PBK) {
#pragma unroll
    for (int c = 0; c < 2; ++c) {
      int r = row0 + c * 16;
      gload_lds16(&A[(size_t)(mbase + r) * EE + kt + chunk * 8], &As[wid * 1024 + c * 512]);
      gload_lds16(&Wot[(size_t)(nbase + r) * EE + kt + chunk * 8], &Bs[wid * 1024 + c * 512]);
    }
    __syncthreads();
    half8 a[4], bfr[4];
#pragma unroll
    for (int i = 0; i < 4; ++i) {
      a[i] = *reinterpret_cast<const half8*>(&As[(wr * 64 + i * 16 + l15) * PBK + l4 * 8]);
      bfr[i] = *reinterpret_cast<const half8*>(&Bs[(wc * 64 + i * 16 + l15) * PBK + l4 * 8]);
    }
#pragma unroll
    for (int mi = 0; mi < 4; ++mi)
#pragma unroll
      for (int ni = 0; ni < 4; ++ni)
        acc[mi][ni] = __builtin_amdgcn_mfma_f32_16x16x32_f16(a[mi], bfr[ni], acc[mi][ni], 0, 0, 0);
    __syncthreads();
  }
#pragma unroll
  for (int mi = 0; mi < 4; ++mi)
#pragma unroll
    for (int ni = 0; ni < 4; ++ni) {
      int n = nbase + wc * 64 + ni * 16 + l15;
      float bb = bo[n];
#pragma unroll
      for (int j = 0; j < 4; ++j) {
        int m = mbase + wr * 64 + mi * 16 + l4 * 4 + j;
        out[(size_t)m * EE + n] = acc[mi][ni][j] + bb;
      }
    }
}

extern "C" void kernel_launch(void* const* d_in, const int* in_sizes, int n_in,
                              void* d_out, int out_size, void* d_ws, size_t ws_size,
                              hipStream_t stream) {
  const float* query = (const float*)d_in[0];
  const float* key_ = (const float*)d_in[1];
  const float* value = (const float*)d_in[2];
  const int* mask = (const int*)d_in[3];
  const float* Wq = (const float*)d_in[4];
  const float* bq = (const float*)d_in[5];
  const float* Wk = (const float*)d_in[6];
  const float* bk = (const float*)d_in[7];
  const float* Wv = (const float*)d_in[8];
  const float* bv = (const float*)d_in[9];
  const float* Wo = (const float*)d_in[10];
  const float* bo = (const float*)d_in[11];
  float* out = (float*)d_out;

  const size_t MH = 1u << 20;                  // halves per 1024x1024 weight
  const size_t QH = (size_t)BB * HH * SS * DH; // 8388608 halves
  h16* wqt = (h16*)d_ws;
  h16* wkt = wqt + MH;
  h16* wvt = wkt + MH;
  h16* wot = wvt + MH;
  h16* qh = wot + MH;
  h16* kh = qh + QH;
  h16* vh = kh + QH;
  h16* ah = vh + QH;
  unsigned* maskw = (unsigned*)(ah + QH);

  mha_pack_mask<<<(BB * SS * SS) / 256, 256, 0, stream>>>(mask, maskw);
  mha_wtrans<<<dim3(32, 32, 4), dim3(32, 8), 0, stream>>>(Wq, Wk, Wv, Wo, wqt, wkt, wvt, wot);
  mha_proj<<<dim3(EE / PTN, (BB * SS) / PTM, 3), 256, 0, stream>>>(
      query, key_, value, wqt, wkt, wvt, bq, bk, bv, qh, kh, vh);
  mha_attn<<<dim3(SS / 128, BB * HH), 256, 0, stream>>>(qh, kh, vh, maskw, ah);
  mha_oproj<<<dim3(EE / PTN, (BB * SS) / PTM), 256, 0, stream>>>(ah, wot, bo, out);
}

// Round 4
// 328.012 us; speedup vs baseline: 1.4072x; 1.2294x over previous
//
#include <hip/hip_runtime.h>

typedef _Float16 h16;
typedef h16 half8 __attribute__((ext_vector_type(8)));
typedef h16 half4v __attribute__((ext_vector_type(4)));
typedef float f32x4 __attribute__((ext_vector_type(4)));

#define BB 4
#define SS 2048
#define EE 1024
#define HH 16
#define DH 64

__device__ __forceinline__ void gload_lds16(const void* g, void* l) {
  __builtin_amdgcn_global_load_lds((const __attribute__((address_space(1))) void*)g,
                                   (__attribute__((address_space(3))) void*)l, 16, 0, 0);
}

// ---------------- mask pack: int32 -> bitmask ----------------
__global__ __launch_bounds__(256) void mha_pack_mask(const int* __restrict__ mask,
                                                     unsigned* __restrict__ maskw) {
  int gid = blockIdx.x * 256 + threadIdx.x;
  unsigned long long bal = __ballot(mask[gid] != 0);
  int lane = threadIdx.x & 63;
  if (lane == 0) maskw[gid >> 5] = (unsigned)bal;
  else if (lane == 32) maskw[gid >> 5] = (unsigned)(bal >> 32);
}

// ---------------- weight transpose + fp32->fp16 ----------------
__global__ __launch_bounds__(256) void mha_wtrans(const float* __restrict__ w0, const float* __restrict__ w1,
                                                  const float* __restrict__ w2, const float* __restrict__ w3,
                                                  h16* __restrict__ o0, h16* __restrict__ o1,
                                                  h16* __restrict__ o2, h16* __restrict__ o3) {
  __shared__ float t[32][33];
  int z = blockIdx.z;
  const float* src = z == 0 ? w0 : z == 1 ? w1 : z == 2 ? w2 : w3;
  h16* dst = z == 0 ? o0 : z == 1 ? o1 : z == 2 ? o2 : o3;
  int x = threadIdx.x, y = threadIdx.y;
  int bx = blockIdx.x * 32, by = blockIdx.y * 32;
#pragma unroll
  for (int i = 0; i < 4; ++i)
    t[y + i * 8][x] = src[(size_t)(by + y + i * 8) * EE + bx + x];
  __syncthreads();
#pragma unroll
  for (int i = 0; i < 4; ++i)
    dst[(size_t)(bx + y + i * 8) * EE + by + x] = (h16)t[x][y + i * 8];
}

// ---------------- fp32 -> fp16 bulk convert (query/key/value) ----------------
__global__ __launch_bounds__(256) void mha_cvt(const float* __restrict__ s0, const float* __restrict__ s1,
                                               const float* __restrict__ s2, h16* __restrict__ d0,
                                               h16* __restrict__ d1, h16* __restrict__ d2) {
  int z = blockIdx.z;
  const float* s = z == 0 ? s0 : z == 1 ? s1 : s2;
  h16* d = z == 0 ? d0 : z == 1 ? d1 : d2;
  size_t i = ((size_t)blockIdx.x * 256 + threadIdx.x) * 8;
  float4 a = *reinterpret_cast<const float4*>(&s[i]);
  float4 b = *reinterpret_cast<const float4*>(&s[i + 4]);
  half8 h;
  h[0] = (h16)a.x; h[1] = (h16)a.y; h[2] = (h16)a.z; h[3] = (h16)a.w;
  h[4] = (h16)b.x; h[5] = (h16)b.y; h[6] = (h16)b.z; h[7] = (h16)b.w;
  *reinterpret_cast<half8*>(&d[i]) = h;
}

// ---------------- QKV projection GEMM (all-f16, gload_lds both operands) ----------------
#define PTM 128
#define PTN 128
#define PBK 32

__global__ __launch_bounds__(256) void mha_proj(
    const h16* __restrict__ Xq, const h16* __restrict__ Xk, const h16* __restrict__ Xv,
    const h16* __restrict__ Wqt, const h16* __restrict__ Wkt, const h16* __restrict__ Wvt,
    const float* __restrict__ bq, const float* __restrict__ bk, const float* __restrict__ bv,
    h16* __restrict__ Oq, h16* __restrict__ Ok, h16* __restrict__ Ov) {
  int z = blockIdx.z;
  const h16* X = z == 0 ? Xq : z == 1 ? Xk : Xv;
  const h16* Wt = z == 0 ? Wqt : z == 1 ? Wkt : Wvt;
  const float* bias = z == 0 ? bq : z == 1 ? bk : bv;
  h16* out = z == 0 ? Oq : z == 1 ? Ok : Ov;

  __shared__ __align__(16) h16 As[PTM * PBK];
  __shared__ __align__(16) h16 Bs[PTN * PBK];

  int tid = threadIdx.x;
  int lane = tid & 63, wid = tid >> 6;
  int l15 = lane & 15, l4 = lane >> 4;
  int wr = wid >> 1, wc = wid & 1;
  int mbase = blockIdx.y * PTM;
  int nbase = blockIdx.x * PTN;

  const f32x4 fz = {0.f, 0.f, 0.f, 0.f};
  f32x4 acc[4][4];
#pragma unroll
  for (int i = 0; i < 4; ++i)
#pragma unroll
    for (int j = 0; j < 4; ++j) acc[i][j] = fz;

  int row0 = wid * 32 + (lane >> 2), chunk = lane & 3;

  for (int kt = 0; kt < EE; kt += PBK) {
#pragma unroll
    for (int c = 0; c < 2; ++c) {
      int r = row0 + c * 16;
      gload_lds16(&X[(size_t)(mbase + r) * EE + kt + chunk * 8], &As[wid * 1024 + c * 512]);
      gload_lds16(&Wt[(size_t)(nbase + r) * EE + kt + chunk * 8], &Bs[wid * 1024 + c * 512]);
    }
    __syncthreads();

    half8 a[4], bfr[4];
#pragma unroll
    for (int i = 0; i < 4; ++i) {
      a[i] = *reinterpret_cast<const half8*>(&As[(wr * 64 + i * 16 + l15) * PBK + l4 * 8]);
      bfr[i] = *reinterpret_cast<const half8*>(&Bs[(wc * 64 + i * 16 + l15) * PBK + l4 * 8]);
    }
#pragma unroll
    for (int mi = 0; mi < 4; ++mi)
#pragma unroll
      for (int ni = 0; ni < 4; ++ni)
        acc[mi][ni] = __builtin_amdgcn_mfma_f32_16x16x32_f16(a[mi], bfr[ni], acc[mi][ni], 0, 0, 0);
    __syncthreads();
  }

  // Q is pre-scaled by log2(e) so attention can use exp2 directly.
  const float qscale = (z == 0) ? 1.44269504088896f : 1.0f;
#pragma unroll
  for (int mi = 0; mi < 4; ++mi) {
#pragma unroll
    for (int ni = 0; ni < 4; ++ni) {
      int n = nbase + wc * 64 + ni * 16 + l15;
      float bv_ = bias[n];
      int h = n >> 6, d = n & 63;
#pragma unroll
      for (int j = 0; j < 4; ++j) {
        int m = mbase + wr * 64 + mi * 16 + l4 * 4 + j;
        int b_ = m >> 11, s = m & 2047;
        h16 hv = (h16)((acc[mi][ni][j] + bv_) * qscale);
        if (z != 2)
          out[(((size_t)(b_ * HH + h)) * SS + s) * DH + d] = hv;       // (B,H,S,D)
        else
          out[(((size_t)(b_ * HH + h)) * DH + d) * SS + s] = hv;       // V transposed (B,H,D,S)
      }
    }
  }
}

// ---------------- flash attention (swapped QK^T, log2 softmax, BFI mask) ----------------
__global__ __launch_bounds__(256) void mha_attn(
    const h16* __restrict__ qh, const h16* __restrict__ kh, const h16* __restrict__ vh,
    const unsigned* __restrict__ maskw, h16* __restrict__ ah) {
  __shared__ __align__(16) h16 Ks[2][64 * 64];
  __shared__ __align__(16) h16 Vs[2][64 * 64];
  __shared__ __align__(16) h16 Ps[4][32 * 64];
  __shared__ uint4 MaskLut[16];

  int bh = blockIdx.y;
  int b_ = bh >> 4, hh = bh & 15;
  int tid = threadIdx.x, lane = tid & 63, wid = tid >> 6;
  int l15 = lane & 15, l4 = lane >> 4;

  if (tid < 16) {
    unsigned n = tid;
    MaskLut[n] = make_uint4((n & 1) ? 0u : ~0u, (n & 2) ? 0u : ~0u,
                            (n & 4) ? 0u : ~0u, (n & 8) ? 0u : ~0u);
  }

  const h16* Qb = qh + (size_t)bh * SS * DH;
  const h16* Kb = kh + (size_t)bh * SS * DH;
  const h16* Vb = vh + (size_t)bh * DH * SS;
  int qrow0 = blockIdx.x * 128 + wid * 32;

  // Q fragments (B-operand layout): lane holds Q[q = l15][k = l4*8..]
  half8 qf[2][2];
#pragma unroll
  for (int mi = 0; mi < 2; ++mi)
#pragma unroll
    for (int kk = 0; kk < 2; ++kk)
      qf[mi][kk] = *reinterpret_cast<const half8*>(&Qb[(size_t)(qrow0 + mi * 16 + l15) * DH + kk * 32 + l4 * 8]);

  float m_run[2] = {-1e30f, -1e30f};
  f32x4 l_vec[2];
  f32x4 oacc[2][4];
  const f32x4 fz = {0.f, 0.f, 0.f, 0.f};
#pragma unroll
  for (int mi = 0; mi < 2; ++mi) {
    l_vec[mi] = fz;
#pragma unroll
    for (int di = 0; di < 4; ++di) oacc[mi][di] = fz;
  }

  const unsigned* mwb = maskw + ((size_t)b_ * SS + qrow0) * 64;

  int srow = wid * 16 + (lane >> 3);
  int schunk = lane & 7;
  int sh0 = l4 * 4;  // nibble shift base for mask extraction

  // prologue: stage tile 0 into buffer 0 + its mask words
#pragma unroll
  for (int c = 0; c < 2; ++c) {
    int r = srow + c * 8;
    int gk = schunk ^ (r & 7);
    gload_lds16(&Kb[(size_t)r * DH + gk * 8], &Ks[0][wid * 1024 + c * 512]);
    gload_lds16(&Vb[(size_t)r * SS + gk * 8], &Vs[0][wid * 1024 + c * 512]);
  }
  unsigned mw[2][2];
  mw[0][0] = mwb[l15 * 64 + 0];
  mw[0][1] = mwb[l15 * 64 + 1];
  mw[1][0] = mwb[(16 + l15) * 64 + 0];
  mw[1][1] = mwb[(16 + l15) * 64 + 1];
  __syncthreads();

  // Masked logits are forced to NEG before the max so the running max tracks
  // the UNMASKED max (keeps packed fp16 p well-scaled; R2's post-exp-only
  // masking let m be inflated by masked logits -> p underflowed fp16).
  const unsigned negb = __float_as_uint(-1e5f);

  h16* Pw = &Ps[wid][0];
  int it = 0;
  for (int tt = 0; tt < SS; tt += 64, it ^= 1) {
    // prefetch next tile (double buffer) + next mask words
    unsigned mwn[2][2] = {{0u, 0u}, {0u, 0u}};
    if (tt + 64 < SS) {
#pragma unroll
      for (int c = 0; c < 2; ++c) {
        int r = srow + c * 8;
        int gk = schunk ^ (r & 7);
        gload_lds16(&Kb[(size_t)(tt + 64 + r) * DH + gk * 8], &Ks[it ^ 1][wid * 1024 + c * 512]);
        gload_lds16(&Vb[(size_t)r * SS + tt + 64 + gk * 8], &Vs[it ^ 1][wid * 1024 + c * 512]);
      }
      int tw = (tt + 64) >> 5;
      mwn[0][0] = mwb[l15 * 64 + tw];
      mwn[0][1] = mwb[l15 * 64 + tw + 1];
      mwn[1][0] = mwb[(16 + l15) * 64 + tw];
      mwn[1][1] = mwb[(16 + l15) * 64 + tw + 1];
    }

    // QK^T, swapped operands: st[mi][ni] = S^T fragment, row = t, col = q
    const h16* Kt = &Ks[it][0];
    half8 kf[4][2];
#pragma unroll
    for (int ni = 0; ni < 4; ++ni) {
      int trow = ni * 16 + l15;
      int sw = trow & 7;
      kf[ni][0] = *reinterpret_cast<const half8*>(&Kt[trow * 64 + (l4 ^ sw) * 8]);
      kf[ni][1] = *reinterpret_cast<const half8*>(&Kt[trow * 64 + ((4 + l4) ^ sw) * 8]);
    }
    f32x4 st[2][4];
    __builtin_amdgcn_s_setprio(1);
#pragma unroll
    for (int mi = 0; mi < 2; ++mi)
#pragma unroll
      for (int ni = 0; ni < 4; ++ni) {
        f32x4 t_ = fz;
        t_ = __builtin_amdgcn_mfma_f32_16x16x32_f16(kf[ni][0], qf[mi][0], t_, 0, 0, 0);
        t_ = __builtin_amdgcn_mfma_f32_16x16x32_f16(kf[ni][1], qf[mi][1], t_, 0, 0, 0);
        st[mi][ni] = t_;
      }
    __builtin_amdgcn_s_setprio(0);

    // mask BEFORE max: masked logit -> -1e5 via BFI select (1 v_bfi_b32/elem);
    // exp2(-1e5 - m) == 0 exactly, so no post-exp zeroing is needed.
#pragma unroll
    for (int mi = 0; mi < 2; ++mi) {
#pragma unroll
      for (int ni = 0; ni < 4; ++ni) {
        unsigned nib = (mw[mi][ni >> 1] >> (sh0 + 16 * (ni & 1))) & 15u;
        uint4 mm = MaskLut[nib];
        st[mi][ni][0] = __uint_as_float((mm.x & __float_as_uint(st[mi][ni][0])) | (~mm.x & negb));
        st[mi][ni][1] = __uint_as_float((mm.y & __float_as_uint(st[mi][ni][1])) | (~mm.y & negb));
        st[mi][ni][2] = __uint_as_float((mm.z & __float_as_uint(st[mi][ni][2])) | (~mm.z & negb));
        st[mi][ni][3] = __uint_as_float((mm.w & __float_as_uint(st[mi][ni][3])) | (~mm.w & negb));
      }
    }

    // online softmax, log2 domain
#pragma unroll
    for (int mi = 0; mi < 2; ++mi) {
      // max tree in max3-fusible triples: 16 values
      float t0 = fmaxf(fmaxf(st[mi][0][0], st[mi][0][1]), st[mi][0][2]);
      float t1 = fmaxf(fmaxf(st[mi][0][3], st[mi][1][0]), st[mi][1][1]);
      float t2 = fmaxf(fmaxf(st[mi][1][2], st[mi][1][3]), st[mi][2][0]);
      float t3 = fmaxf(fmaxf(st[mi][2][1], st[mi][2][2]), st[mi][2][3]);
      float t4 = fmaxf(fmaxf(st[mi][3][0], st[mi][3][1]), st[mi][3][2]);
      float tmax = fmaxf(fmaxf(fmaxf(t0, t1), fmaxf(t2, t3)), fmaxf(t4, st[mi][3][3]));
      tmax = fmaxf(tmax, __shfl_xor(tmax, 16));
      tmax = fmaxf(tmax, __shfl_xor(tmax, 32));
      // T13 defer-max: rescale only when max grew by > 8 (2^8 headroom in f16)
      if (!__all(tmax - m_run[mi] <= 8.0f)) {
        float mnew = fmaxf(m_run[mi], tmax);
        float sc = __builtin_amdgcn_exp2f(m_run[mi] - mnew);
        l_vec[mi] *= sc;
#pragma unroll
        for (int di = 0; di < 4; ++di) oacc[mi][di] *= sc;
        m_run[mi] = mnew;
      }
      float mneg = -m_run[mi];
#pragma unroll
      for (int ni = 0; ni < 4; ++ni)
#pragma unroll
        for (int j = 0; j < 4; ++j)
          st[mi][ni][j] = __builtin_amdgcn_exp2f(st[mi][ni][j] + mneg);
      // deferred sum: vector accumulate, horizontal once at the end
      l_vec[mi] += (st[mi][0] + st[mi][1]) + (st[mi][2] + st[mi][3]);
    }

    // pack P -> per-wave LDS [q][t], 16B-chunk XOR swizzle
#pragma unroll
    for (int mi = 0; mi < 2; ++mi) {
      int q = mi * 16 + l15;
#pragma unroll
      for (int ni = 0; ni < 4; ++ni) {
        auto pa = __builtin_amdgcn_cvt_pkrtz(st[mi][ni][0], st[mi][ni][1]);
        auto pb = __builtin_amdgcn_cvt_pkrtz(st[mi][ni][2], st[mi][ni][3]);
        half4v w;
        w[0] = pa[0]; w[1] = pa[1]; w[2] = pb[0]; w[3] = pb[1];
        int c16 = (ni * 2 + (l4 >> 1)) ^ (q & 7);
        *reinterpret_cast<half4v*>(&Pw[q * 64 + c16 * 8 + (l4 & 1) * 4]) = w;
      }
    }

    // PV: O^T += V^T * P^T  (row = d, col = q)
    const h16* Vt = &Vs[it][0];
    half8 vf[4][2], pf[2][2];
#pragma unroll
    for (int di = 0; di < 4; ++di) {
      int dr = di * 16 + l15, sw = dr & 7;
      vf[di][0] = *reinterpret_cast<const half8*>(&Vt[dr * 64 + (l4 ^ sw) * 8]);
      vf[di][1] = *reinterpret_cast<const half8*>(&Vt[dr * 64 + ((4 + l4) ^ sw) * 8]);
    }
#pragma unroll
    for (int mi = 0; mi < 2; ++mi) {
      int q = mi * 16 + l15;
      pf[mi][0] = *reinterpret_cast<const half8*>(&Pw[q * 64 + ((l4 ^ (q & 7)) * 8)]);
      pf[mi][1] = *reinterpret_cast<const half8*>(&Pw[q * 64 + (((4 + l4) ^ (q & 7)) * 8)]);
    }
    __builtin_amdgcn_s_setprio(1);
#pragma unroll
    for (int mi = 0; mi < 2; ++mi)
#pragma unroll
      for (int di = 0; di < 4; ++di) {
        oacc[mi][di] = __builtin_amdgcn_mfma_f32_16x16x32_f16(vf[di][0], pf[mi][0], oacc[mi][di], 0, 0, 0);
        oacc[mi][di] = __builtin_amdgcn_mfma_f32_16x16x32_f16(vf[di][1], pf[mi][1], oacc[mi][di], 0, 0, 0);
      }
    __builtin_amdgcn_s_setprio(0);

    mw[0][0] = mwn[0][0]; mw[0][1] = mwn[0][1];
    mw[1][0] = mwn[1][0]; mw[1][1] = mwn[1][1];
    __syncthreads();
  }

  // epilogue: /= (l * sqrt(64)); lane owns q = mi*16+l15, d = di*16+l4*4+j
#pragma unroll
  for (int mi = 0; mi < 2; ++mi) {
    float l = (l_vec[mi][0] + l_vec[mi][1]) + (l_vec[mi][2] + l_vec[mi][3]);
    l += __shfl_xor(l, 16);
    l += __shfl_xor(l, 32);
    float inv = 1.f / (l * 8.f);
    size_t rowb = ((size_t)b_ * SS + (qrow0 + mi * 16 + l15)) * EE + hh * DH;
#pragma unroll
    for (int di = 0; di < 4; ++di) {
      half4v w;
#pragma unroll
      for (int j = 0; j < 4; ++j) w[j] = (h16)(oacc[mi][di][j] * inv);
      *reinterpret_cast<half4v*>(&ah[rowb + di * 16 + l4 * 4]) = w;
    }
  }
}

// ---------------- output projection GEMM ----------------
__global__ __launch_bounds__(256) void mha_oproj(
    const h16* __restrict__ A, const h16* __restrict__ Wot,
    const float* __restrict__ bo, float* __restrict__ out) {
  __shared__ __align__(16) h16 As[PTM * PBK];
  __shared__ __align__(16) h16 Bs[PTN * PBK];
  int tid = threadIdx.x, lane = tid & 63, wid = tid >> 6;
  int l15 = lane & 15, l4 = lane >> 4;
  int wr = wid >> 1, wc = wid & 1;
  int mbase = blockIdx.y * PTM, nbase = blockIdx.x * PTN;
  const f32x4 fz = {0.f, 0.f, 0.f, 0.f};
  f32x4 acc[4][4];
#pragma unroll
  for (int i = 0; i < 4; ++i)
#pragma unroll
    for (int j = 0; j < 4; ++j) acc[i][j] = fz;
  int row0 = wid * 32 + (lane >> 2), chunk = lane & 3;
  for (int kt = 0; kt < EE; kt += PBK) {
#pragma unroll
    for (int c = 0; c < 2; ++c) {
      int r = row0 + c * 16;
      gload_lds16(&A[(size_t)(mbase + r) * EE + kt + chunk * 8], &As[wid * 1024 + c * 512]);
      gload_lds16(&Wot[(size_t)(nbase + r) * EE + kt + chunk * 8], &Bs[wid * 1024 + c * 512]);
    }
    __syncthreads();
    half8 a[4], bfr[4];
#pragma unroll
    for (int i = 0; i < 4; ++i) {
      a[i] = *reinterpret_cast<const half8*>(&As[(wr * 64 + i * 16 + l15) * PBK + l4 * 8]);
      bfr[i] = *reinterpret_cast<const half8*>(&Bs[(wc * 64 + i * 16 + l15) * PBK + l4 * 8]);
    }
#pragma unroll
    for (int mi = 0; mi < 4; ++mi)
#pragma unroll
      for (int ni = 0; ni < 4; ++ni)
        acc[mi][ni] = __builtin_amdgcn_mfma_f32_16x16x32_f16(a[mi], bfr[ni], acc[mi][ni], 0, 0, 0);
    __syncthreads();
  }
#pragma unroll
  for (int mi = 0; mi < 4; ++mi)
#pragma unroll
    for (int ni = 0; ni < 4; ++ni) {
      int n = nbase + wc * 64 + ni * 16 + l15;
      float bb = bo[n];
#pragma unroll
      for (int j = 0; j < 4; ++j) {
        int m = mbase + wr * 64 + mi * 16 + l4 * 4 + j;
        out[(size_t)m * EE + n] = acc[mi][ni][j] + bb;
      }
    }
}

extern "C" void kernel_launch(void* const* d_in, const int* in_sizes, int n_in,
                              void* d_out, int out_size, void* d_ws, size_t ws_size,
                              hipStream_t stream) {
  const float* query = (const float*)d_in[0];
  const float* key_ = (const float*)d_in[1];
  const float* value = (const float*)d_in[2];
  const int* mask = (const int*)d_in[3];
  const float* Wq = (const float*)d_in[4];
  const float* bq = (const float*)d_in[5];
  const float* Wk = (const float*)d_in[6];
  const float* bk = (const float*)d_in[7];
  const float* Wv = (const float*)d_in[8];
  const float* bv = (const float*)d_in[9];
  const float* Wo = (const float*)d_in[10];
  const float* bo = (const float*)d_in[11];
  float* out = (float*)d_out;

  const size_t MH = 1u << 20;                  // halves per 1024x1024 weight
  const size_t QH = (size_t)BB * HH * SS * DH; // 8388608 halves
  h16* wqt = (h16*)d_ws;
  h16* wkt = wqt + MH;
  h16* wvt = wkt + MH;
  h16* wot = wvt + MH;
  h16* qh = wot + MH;
  h16* kh = qh + QH;
  h16* vh = kh + QH;
  h16* ah = vh + QH;
  unsigned* maskw = (unsigned*)(ah + QH);

  // f16 input scratch: xq aliases the ah slot (dead before attn writes ah);
  // xk/xv live inside d_out (exactly 2*QH halves; dead until oproj overwrites).
  h16* xq = ah;
  h16* xk = (h16*)d_out;
  h16* xv = xk + QH;

  mha_pack_mask<<<(BB * SS * SS) / 256, 256, 0, stream>>>(mask, maskw);
  mha_wtrans<<<dim3(32, 32, 4), dim3(32, 8), 0, stream>>>(Wq, Wk, Wv, Wo, wqt, wkt, wvt, wot);
  mha_cvt<<<dim3((BB * SS * EE) / 2048, 1, 3), 256, 0, stream>>>(query, key_, value, xq, xk, xv);
  mha_proj<<<dim3(EE / PTN, (BB * SS) / PTM, 3), 256, 0, stream>>>(
      xq, xk, xv, wqt, wkt, wvt, bq, bk, bv, qh, kh, vh);
  mha_attn<<<dim3(SS / 128, BB * HH), 256, 0, stream>>>(qh, kh, vh, maskw, ah);
  mha_oproj<<<dim3(EE / PTN, (BB * SS) / PTM), 256, 0, stream>>>(ah, wot, bo, out);
}